// Round 12
// baseline (154.841 us; speedup 1.0000x reference)
//
#include <hip/hip_runtime.h>
#include <hip/hip_bf16.h>
#include <math.h>

#define BB 4
#define CC 256
#define DKK 32
#define NN 4096
// 1/sqrt(32) * log2(e) — folded into q at QKV epilogue; attention uses exp2.
#define QSCALE 0.2550181864060454f

typedef __attribute__((ext_vector_type(8))) __bf16 bf16x8;
typedef __attribute__((ext_vector_type(4))) __bf16 bf16x4;
typedef __attribute__((ext_vector_type(4))) float f32x4;
typedef __attribute__((ext_vector_type(16))) float f32x16;

// ---------------------------------------------------------------------------
// Kernel 1: fused x-transpose + QKV projection (identical to R11 except the
// V store slot permutation).
// V TILED + SLOT-PERMUTED for the LDS-free attention PV:
//   per 32-n chunk, 8 c-tiles x 2 ks-halves of [32 c][16 slots], where slot
//   s = lh*8+t holds n = (t&3) + 8*(t>>2) + 4*lh  (+16*ks). This makes the
//   V A-frag k-enumeration match the KQ 32x32 D-layout's natural n order, so
//   P can feed PV directly from registers (no LDS round-trip in attn).
//   Inverse used here: slot(n&15=r) = 8*((r>>2)&1) + (r&3) + 4*((r>>3)&1).
// ---------------------------------------------------------------------------
#define XST 260      // xsT row stride (bf16 elems)
#define SCRST 33     // q/k scratch row stride (fp32)

__global__ __launch_bounds__(256, 2) void qkv_kernel(
    const float* __restrict__ x,
    const float* __restrict__ Wq, const float* __restrict__ bq,
    const float* __restrict__ Wk, const float* __restrict__ bk,
    const float* __restrict__ Wv, const float* __restrict__ bv,
    __bf16* __restrict__ qws, __bf16* __restrict__ kws, __bf16* __restrict__ vws)
{
    __shared__ __align__(16) unsigned char smem[16640];
    __bf16* xsT = (__bf16*)smem;
    float*  scr = (float*)smem;

    const int tid = threadIdx.x;
    const int w   = tid >> 6;
    const int l   = tid & 63;
    const int l15 = l & 15;
    const int lq  = l >> 4;
    const int n0  = blockIdx.x * 32;
    const int b   = blockIdx.y;

    // ---- staging: thread reads float4 (4 n, 1 c), writes 4 bf16 scalars ----
    {
        const int cb = tid >> 3;
        const int nf = (tid & 7) * 4;
        const float* xp = x + ((size_t)(b * CC) + cb) * NN + n0 + nf;
#pragma unroll
        for (int r = 0; r < 8; r++) {
            float4 v = *(const float4*)(xp + (size_t)r * 32 * NN);
            int c = r * 32 + cb;
            xsT[(nf + 0) * XST + c] = (__bf16)v.x;
            xsT[(nf + 1) * XST + c] = (__bf16)v.y;
            xsT[(nf + 2) * XST + c] = (__bf16)v.z;
            xsT[(nf + 3) * XST + c] = (__bf16)v.w;
        }
    }

    const float* wp[5];
#pragma unroll
    for (int ot = 0; ot < 5; ot++) {
        int ob = 80 * w + 16 * ot;
        const float* src = (ob < 32) ? (Wq + (size_t)ob * CC)
                         : (ob < 64) ? (Wk + (size_t)(ob - 32) * CC)
                                     : (Wv + (size_t)(ob - 64) * CC);
        wp[ot] = src + (size_t)l15 * CC;
    }

    float4 wc[5][2], wn[5][2];
#pragma unroll
    for (int ot = 0; ot < 5; ot++) {
        wc[ot][0] = *(const float4*)(wp[ot] + lq * 8);
        wc[ot][1] = *(const float4*)(wp[ot] + lq * 8 + 4);
    }

    __syncthreads();

    const f32x4 zf = {0.f, 0.f, 0.f, 0.f};
    f32x4 acc[5][2];
#pragma unroll
    for (int i = 0; i < 5; i++)
#pragma unroll
        for (int j = 0; j < 2; j++) acc[i][j] = zf;

#pragma unroll
    for (int ks = 0; ks < 8; ks++) {
        if (ks < 7) {
#pragma unroll
            for (int ot = 0; ot < 5; ot++) {
                wn[ot][0] = *(const float4*)(wp[ot] + (ks + 1) * 32 + lq * 8);
                wn[ot][1] = *(const float4*)(wp[ot] + (ks + 1) * 32 + lq * 8 + 4);
            }
        }
        bf16x8 bfr[2];
#pragma unroll
        for (int nt = 0; nt < 2; nt++) {
            bf16x4 lo = *(const bf16x4*)&xsT[(nt * 16 + l15) * XST + ks * 32 + lq * 8];
            bf16x4 hi = *(const bf16x4*)&xsT[(nt * 16 + l15) * XST + ks * 32 + lq * 8 + 4];
            bfr[nt] = __builtin_shufflevector(lo, hi, 0, 1, 2, 3, 4, 5, 6, 7);
        }
#pragma unroll
        for (int ot = 0; ot < 5; ot++) {
            bf16x8 af;
            af[0] = (__bf16)wc[ot][0].x; af[1] = (__bf16)wc[ot][0].y;
            af[2] = (__bf16)wc[ot][0].z; af[3] = (__bf16)wc[ot][0].w;
            af[4] = (__bf16)wc[ot][1].x; af[5] = (__bf16)wc[ot][1].y;
            af[6] = (__bf16)wc[ot][1].z; af[7] = (__bf16)wc[ot][1].w;
#pragma unroll
            for (int nt = 0; nt < 2; nt++)
                acc[ot][nt] = __builtin_amdgcn_mfma_f32_16x16x32_bf16(af, bfr[nt], acc[ot][nt], 0, 0, 0);
        }
        if (ks < 7) {
#pragma unroll
            for (int ot = 0; ot < 5; ot++) { wc[ot][0] = wn[ot][0]; wc[ot][1] = wn[ot][1]; }
        }
    }

    __syncthreads();

    // ---- epilogue ----
    // V slot permutation (per-lane constant): r = l15
    const int voff = ((l15 >> 2) & 1) * 8 + (l15 & 3) + ((l15 >> 3) & 1) * 4;
    __bf16* vchunk = vws + (size_t)b * CC * NN + (size_t)(n0 >> 5) * 8192;
#pragma unroll
    for (int ot = 0; ot < 5; ot++) {
        int ob = 80 * w + ot * 16;
#pragma unroll
        for (int nt = 0; nt < 2; nt++) {
#pragma unroll
            for (int r = 0; r < 4; r++) {
                int o = ob + lq * 4 + r;
                int n = nt * 16 + l15;
                float val = acc[ot][nt][r];
                if (ob >= 64) {
                    int c = o - 64;
                    vchunk[(c >> 5) * 1024 + nt * 512 + (c & 31) * 16 + voff] =
                        (__bf16)(val + bv[c]);
                } else if (ob < 32) {
                    scr[o * SCRST + n] = (val + bq[o]) * QSCALE;
                } else {
                    scr[o * SCRST + n] = val + bk[o - 32];
                }
            }
        }
    }
    __syncthreads();
    {
        int n  = tid >> 3;
        int d0 = (tid & 7) * 4;
        bf16x4 qv, kv;
#pragma unroll
        for (int j = 0; j < 4; j++) {
            qv[j] = (__bf16)scr[(d0 + j) * SCRST + n];
            kv[j] = (__bf16)scr[(32 + d0 + j) * SCRST + n];
        }
        size_t base = ((size_t)b * NN + n0 + n) * DKK + d0;
        *(bf16x4*)&qws[base] = qv;
        *(bf16x4*)&kws[base] = kv;
    }
}

// ---------------------------------------------------------------------------
// Kernel 2: flash attention — FULLY REGISTER-RESIDENT main loop.
// n-split waves, 64m x 128c blocks, grid 512 (2 blocks/CU = 2 waves/SIMD).
// KQ computed as mfma_32x32x16(A=K, B=Q): D col = m = lane&31 (matches PV
// B-operand lane index), rows n in the (reg,lh)-order that V's permuted
// tiling reproduces on the A side -> P feeds PV straight from registers.
// Zero LDS, zero barriers, zero cross-lane ops in the main loop.
// acc 128 AGPR + ~115 VGPR -> 2 waves/SIMD.
// ---------------------------------------------------------------------------
#define MST 68                     // O-reduce row stride (dwords)

__global__ __launch_bounds__(256, 2) void attn_kernel(
    const __bf16* __restrict__ qb, const __bf16* __restrict__ kb,
    const __bf16* __restrict__ vt, const float* __restrict__ x,
    float* __restrict__ out)
{
    // [0, 34816)      Ored: 4 waves x 32 x MST fp32 (epilogue only)
    // [34816, 35840)  Ls[4][64]
    // [35840, 36096)  Linv[64]
    __shared__ __align__(16) unsigned char smem[36096];
    float* Ls   = (float*)(smem + 34816);
    float* Linv = (float*)(smem + 35840);

    const int tid = threadIdx.x;
    const int w   = tid >> 6;
    const int l   = tid & 63;
    const int l31 = l & 31;
    const int lh  = l >> 5;

    // XCD swizzle: batch pinned to an XCD pair -> K/V/Q stay L2-resident
    const int beta = blockIdx.x;
    const int b    = (beta >> 1) & 3;
    const int ch   = (beta >> 3) & 1;
    const int mt   = ((beta >> 4) << 1) | (beta & 1);
    const int m0   = mt * 64;

    const __bf16* qbb = qb + (size_t)b * NN * DKK;
    const __bf16* kbb = kb + (size_t)b * NN * DKK;
    const __bf16* vtb = vt + (size_t)b * CC * NN;

    // Q B-frags: B[k=d][j=m]: lane j=l31, k-slot = lh*8+t -> d = kc*16+lh*8+t
    bf16x8 qa[2][2];
#pragma unroll
    for (int mt2 = 0; mt2 < 2; mt2++)
#pragma unroll
        for (int kc = 0; kc < 2; kc++)
            qa[mt2][kc] = *(const bf16x8*)(qbb + (size_t)(m0 + mt2 * 32 + l31) * DKK
                                           + kc * 16 + lh * 8);

    // K A-frags: A[i=n][k=d]: lane i=l31 (n within strip), d = kc*16+lh*8+t
    const __bf16* kstrip = kbb + (size_t)(w * 32 + l31) * DKK + lh * 8;
    // V A-frags (permuted tiling): base + ic*32768 + ct*1024 + ks*512
    const __bf16* vstrip = vtb + (size_t)w * 8192 + (size_t)ch * 4096
                               + l31 * 16 + lh * 8;

    const f32x16 z16 = {0.f,0.f,0.f,0.f,0.f,0.f,0.f,0.f,
                        0.f,0.f,0.f,0.f,0.f,0.f,0.f,0.f};
    f32x16 acc32[2][4];
#pragma unroll
    for (int i = 0; i < 2; i++)
#pragma unroll
        for (int j = 0; j < 4; j++) acc32[i][j] = z16;
    float lacc[2] = {0.f, 0.f};

    // prologue: k frags for chunk 0
    bf16x8 kf0 = *(const bf16x8*)kstrip;
    bf16x8 kf1 = *(const bf16x8*)(kstrip + 16);

    // ---- main loop: no LDS, no barriers, no cross-lane ----
#pragma unroll 2
    for (int ic = 0; ic < 32; ic++) {
        const __bf16* vch = vstrip + (size_t)ic * 32768;

        // V A-frags for this chunk (8 x b128; KQ+exp covers their latency)
        bf16x8 vf[4][2];
#pragma unroll
        for (int ct = 0; ct < 4; ct++) {
            vf[ct][0] = *(const bf16x8*)(vch + ct * 1024);
            vf[ct][1] = *(const bf16x8*)(vch + ct * 1024 + 512);
        }

        // KQ: e[mt2] = K_strip(32n x 32d) . Q(mt2 tile)^T  (2 chained k-halves)
        f32x16 e0 = __builtin_amdgcn_mfma_f32_32x32x16_bf16(kf0, qa[0][0], z16, 0, 0, 0);
        e0 = __builtin_amdgcn_mfma_f32_32x32x16_bf16(kf1, qa[0][1], e0, 0, 0, 0);
        f32x16 e1 = __builtin_amdgcn_mfma_f32_32x32x16_bf16(kf0, qa[1][0], z16, 0, 0, 0);
        e1 = __builtin_amdgcn_mfma_f32_32x32x16_bf16(kf1, qa[1][1], e1, 0, 0, 0);

        // prefetch k for chunk ic+1 (OOB at ic=31 lands in vws region — unused)
        kf0 = *(const bf16x8*)(kstrip + (size_t)(ic + 1) * 128 * DKK);
        kf1 = *(const bf16x8*)(kstrip + (size_t)(ic + 1) * 128 * DKK + 16);

        // exp2 + pack P into B-frags in register (reg order == k-slot order)
        bf16x8 pb0[2], pb1[2];
#pragma unroll
        for (int r = 0; r < 16; r++) {
            float v = __builtin_amdgcn_exp2f(e0[r]);
            lacc[0] += v;
            pb0[r >> 3][r & 7] = (__bf16)v;
        }
#pragma unroll
        for (int r = 0; r < 16; r++) {
            float v = __builtin_amdgcn_exp2f(e1[r]);
            lacc[1] += v;
            pb1[r >> 3][r & 7] = (__bf16)v;
        }

        // PV: acc[c-tile][m-tile] += V . P  (16 MFMAs of 32x32x16)
#pragma unroll
        for (int ct = 0; ct < 4; ct++) {
            acc32[0][ct] = __builtin_amdgcn_mfma_f32_32x32x16_bf16(vf[ct][0], pb0[0], acc32[0][ct], 0, 0, 0);
            acc32[0][ct] = __builtin_amdgcn_mfma_f32_32x32x16_bf16(vf[ct][1], pb0[1], acc32[0][ct], 0, 0, 0);
            acc32[1][ct] = __builtin_amdgcn_mfma_f32_32x32x16_bf16(vf[ct][0], pb1[0], acc32[1][ct], 0, 0, 0);
            acc32[1][ct] = __builtin_amdgcn_mfma_f32_32x32x16_bf16(vf[ct][1], pb1[1], acc32[1][ct], 0, 0, 0);
        }
    }

    // ---- l: combine the two lh halves (each n counted once per half) ----
#pragma unroll
    for (int mt2 = 0; mt2 < 2; mt2++)
        lacc[mt2] += __shfl_xor(lacc[mt2], 32, 64);
    if (lh == 0) {
        Ls[w * 64 + l31]      = lacc[0];
        Ls[w * 64 + 32 + l31] = lacc[1];
    }
    __syncthreads();
    if (tid < 64)
        Linv[tid] = 1.0f / (Ls[tid] + Ls[64 + tid] + Ls[128 + tid] + Ls[192 + tid]);

    // ---- epilogue: cross-wave O reduce in 4 quarters of 32 c ----
    // acc32 D-layout: col m = l31 (+32*mt2); row c = (reg&3)+8*(reg>>2)+4*lh
    float* Ored = (float*)smem + w * (32 * MST);
#pragma unroll
    for (int q = 0; q < 4; q++) {
        if (q > 0) __syncthreads();
#pragma unroll
        for (int mt2 = 0; mt2 < 2; mt2++) {
#pragma unroll
            for (int reg = 0; reg < 16; reg++) {
                int row = (reg & 3) + 8 * (reg >> 2) + 4 * lh;
                Ored[row * MST + mt2 * 32 + l31] = acc32[mt2][q][reg];
            }
        }
        __syncthreads();
        const int cl  = tid >> 3;
        const int mi0 = (tid & 7) * 8;
        const float* Ob = (const float*)smem + cl * MST;
#pragma unroll
        for (int j = 0; j < 2; j++) {
            int mi = mi0 + 4 * j;
            f32x4 s = *(const f32x4*)&Ob[mi];
            s = s + *(const f32x4*)&Ob[1 * (32 * MST) + mi];
            s = s + *(const f32x4*)&Ob[2 * (32 * MST) + mi];
            s = s + *(const f32x4*)&Ob[3 * (32 * MST) + mi];
            f32x4 li = *(const f32x4*)&Linv[mi];
            int c = ch * 128 + q * 32 + cl;
            size_t gi = ((size_t)(b * CC + c)) * NN + m0 + mi;
            f32x4 xr = *(const f32x4*)&x[gi];
            *(f32x4*)&out[gi] = s * li + xr;
        }
    }
}

extern "C" void kernel_launch(void* const* d_in, const int* in_sizes, int n_in,
                              void* d_out, int out_size, void* d_ws, size_t ws_size,
                              hipStream_t stream) {
    const float* x  = (const float*)d_in[0];
    const float* Wq = (const float*)d_in[1];
    const float* bq = (const float*)d_in[2];
    const float* Wk = (const float*)d_in[3];
    const float* bk = (const float*)d_in[4];
    const float* Wv = (const float*)d_in[5];
    const float* bv = (const float*)d_in[6];
    float* out = (float*)d_out;

    __bf16* qws = (__bf16*)d_ws;                       // B*N*32
    __bf16* kws = qws + (size_t)BB * NN * DKK;         // B*N*32
    __bf16* vws = kws + (size_t)BB * NN * DKK;         // B*C*N (tiled+permuted)

    qkv_kernel<<<dim3(128, BB), 256, 0, stream>>>(x, Wq, bq, Wk, bk, Wv, bv,
                                                  qws, kws, vws);
    attn_kernel<<<dim3(512), 256, 0, stream>>>(qws, kws, vws, x, out);
}